// Round 18
// baseline (292.729 us; speedup 1.0000x reference)
//
#include <hip/hip_runtime.h>
#include <cfloat>

#define BB 2
#define NN 8192
#define OO 64
#define KK 20
#define QB 128        // queries per kS block (4 waves x 32)
#define MS 8          // point splits in kS (L2 locality > occupancy, r12/r13)
#define CHUNK 1024    // points per kS split
#define CAPQ 192      // candidate slots per query (tight thr: mean ~80)
#define RB 9          // kS per-lane buffer depth (mean ~5/chunk)
#define RBS 10        // lbuf stride in u64; writes sparse -> conflicts moot

using f16x8  = __attribute__((ext_vector_type(8))) _Float16;
using f32x16 = __attribute__((ext_vector_type(16))) float;
typedef unsigned long long u64;

// ws layout (float units)
#define XH_OFF ((size_t)0)
#define XL_OFF (XH_OFF + (size_t)BB*NN*32)
#define SQ_OFF (XL_OFF + (size_t)BB*NN*32)        // B*N
#define Y1_OFF (SQ_OFF + (size_t)BB*NN)           // B*N*64 (n-major rows)
#define Y2_OFF (Y1_OFF + (size_t)BB*NN*64)        // B*N*64 (n-major rows)
#define TH_OFF (Y2_OFF + (size_t)BB*NN*64)        // B*N thresholds (float)
#define CN_OFF (TH_OFF + (size_t)BB*NN)           // B*N counters (int)
#define TL_OFF (CN_OFF + (size_t)BB*NN)           // 2*B*N*KK half-sample top-20 lists
#define CA_OFF (TL_OFF + (size_t)2*BB*NN*KK)      // B*N*CAPQ u64
#define IX_OFF (CA_OFF + (size_t)BB*NN*CAPQ*2)    // B*N*K (int)
#define HX_OFF (IX_OFF + (size_t)BB*NN*KK)        // B*64*N (o-major)
#define HN_OFF (HX_OFF + (size_t)BB*NN*64)        // B*64*N (o-major)
#define ST_OFF (HN_OFF + (size_t)BB*NN*64)        // 128

// MFMA-native swizzled fragment layout (verified r6-17)
__device__ __forceinline__ size_t frag_off(int b, int tile, int t, int lane) {
    return ((((size_t)b * (NN / 32) + tile) * 4 + t) * 64 + lane) * 8;
}

// order-preserving float->uint map (works for negatives too)
__device__ __forceinline__ unsigned fmap(float f) {
    unsigned u = __float_as_uint(f);
    return (u & 0x80000000u) ? ~u : (u | 0x80000000u);
}

// ---------- branchless selection primitives ----------
__device__ __forceinline__ void sort16(float* v) {      // bitonic, ascending
#pragma unroll
    for (int k = 2; k <= 16; k <<= 1) {
#pragma unroll
        for (int j = k >> 1; j > 0; j >>= 1) {
#pragma unroll
            for (int i = 0; i < 16; ++i) {
                int l = i ^ j;
                if (l > i) {
                    bool up = ((i & k) == 0);
                    float mn = fminf(v[i], v[l]);
                    float mx = fmaxf(v[i], v[l]);
                    v[i] = up ? mn : mx;
                    v[l] = up ? mx : mn;
                }
            }
        }
    }
}
__device__ __forceinline__ void bmerge32(float* A) {    // bitonic input -> ascending
#pragma unroll
    for (int j = 16; j > 0; j >>= 1) {
#pragma unroll
        for (int i = 0; i < 32; ++i) {
            if ((i & j) == 0) {
                float mn = fminf(A[i], A[i | j]);
                float mx = fmaxf(A[i], A[i | j]);
                A[i] = mn;
                A[i | j] = mx;
            }
        }
    }
}
// A(32, asc) <- 32 smallest of A U B(16, asc)
__device__ __forceinline__ void merge32_16(float* A, const float* B) {
#pragma unroll
    for (int i = 16; i < 32; ++i) A[i] = fminf(A[i], B[31 - i]);
    bmerge32(A);
}
// A(32, asc) <- 32 smallest of A U B(32, asc)
__device__ __forceinline__ void merge32_32(float* A, const float* B) {
    float t[32];
#pragma unroll
    for (int i = 0; i < 32; ++i) t[i] = fminf(A[i], B[31 - i]);
    bmerge32(t);
#pragma unroll
    for (int i = 0; i < 32; ++i) A[i] = t[i];
}

// ---------- distance tile pieces: 32 points x 32 queries, hi/lo fp16 MFMA ----------
// C: col=lane&31 (query), row = (i&3) + 8*(i>>2) + 4*kh.  Verified rounds 3-17.
__device__ __forceinline__ void load_atile(const _Float16* __restrict__ xh,
                                           const _Float16* __restrict__ xl,
                                           int b, int ptile, int lane,
                                           f16x8* Ah, f16x8* Al) {
#pragma unroll
    for (int t = 0; t < 4; ++t) {
        size_t o = frag_off(b, ptile, t, lane);
        Ah[t] = *(const f16x8*)&xh[o];   // coalesced: 64 lanes x 16 B contiguous
        Al[t] = *(const f16x8*)&xl[o];
    }
}

// sqs: LDS-staged sq slice (lgkmcnt path, keeps A loads alone on vmcnt)
__device__ __forceinline__ void dist_from_frags(const f16x8* Ah, const f16x8* Al,
                                                const float* sqs, int sbase, int kh,
                                                const f16x8* Qh, const f16x8* Ql,
                                                float* dv) {
    f32x16 c0, c1;
#pragma unroll
    for (int i = 0; i < 16; ++i) { c0[i] = 0.f; c1[i] = 0.f; }
#pragma unroll
    for (int t = 0; t < 4; ++t) {
        c0 = __builtin_amdgcn_mfma_f32_32x32x16_f16(Ah[t], Qh[t], c0, 0, 0, 0); // hi*hi
        c1 = __builtin_amdgcn_mfma_f32_32x32x16_f16(Ah[t], Ql[t], c1, 0, 0, 0); // hi*lo
        c1 = __builtin_amdgcn_mfma_f32_32x32x16_f16(Al[t], Qh[t], c1, 0, 0, 0); // lo*hi
    }
#pragma unroll
    for (int r2 = 0; r2 < 4; ++r2) {
        float4 sv = *(const float4*)&sqs[sbase + 8 * r2 + 4 * kh];  // LDS broadcast
        float svv[4] = {sv.x, sv.y, sv.z, sv.w};
#pragma unroll
        for (int j = 0; j < 4; ++j) {
            int i = r2 * 4 + j;
            float d = fmaf(-2.f, c0[i], svv[j]);      // d = sq[p] - 2*dot (sq[q] const)
            dv[i] = fmaf(-9.765625e-4f, c1[i], d);    // cross terms * 2 * 2^-11
        }
    }
}

__device__ __forceinline__ void load_qfrag(const _Float16* __restrict__ xh,
                                           const _Float16* __restrict__ xl,
                                           int b, int qbase, int lane,
                                           f16x8* Qh, f16x8* Ql) {
    const int qtile = qbase >> 5;
#pragma unroll
    for (int t = 0; t < 4; ++t) {
        size_t o = frag_off(b, qtile, t, lane);
        Qh[t] = *(const f16x8*)&xh[o];
        Ql[t] = *(const f16x8*)&xl[o];
    }
}

// ---------------- kernel A: sq + fp16 hi/lo split (swizzled) + y1/y2 ----------------
// r17 structure: x staged in LDS once; o-split into 2 groups of 32.
__global__ void __launch_bounds__(256, 2)
kA(const float* __restrict__ x, const float* __restrict__ W,
   float* __restrict__ ws) {
    __shared__ __align__(16) float w1s[32 * 64];   // 8 KB: this block's 32 o rows
    __shared__ __align__(16) float w2s[32 * 64];   // 8 KB
    __shared__ float xs[64 * 65];                  // 16.6 KB [c][n], pad 65
    __shared__ float tb[64 * 33];                  // 8.4 KB transpose, pad 33
    const int bb = blockIdx.z;
    const int og = blockIdx.y;        // o-group: 0 or 1
    const int obase = og * 32;
    const int nbase = blockIdx.x * 64;
    const int tn = threadIdx.x & 63, tq = threadIdx.x >> 6;

    // W slice (32 o x 64 c), w2 = W_right - W_left
    for (int i = threadIdx.x; i < 2048; i += 256) {
        int ol = i >> 6, c = i & 63;
        float a = W[(obase + ol) * 128 + c];
        float d = W[(obase + ol) * 128 + 64 + c];
        w1s[i] = a;
        w2s[i] = d - a;
    }
    // x tile: [c][n] staged coalesced (256 B per row-segment)
    for (int i = threadIdx.x; i < 4096; i += 256) {
        int c = i >> 6, nl = i & 63;
        xs[c * 65 + nl] = x[((size_t)bb * 64 + c) * NN + nbase + nl];
    }
    if (og == 0) {
        if (blockIdx.x == 0 && bb == 0 && threadIdx.x < 128)
            ws[ST_OFF + threadIdx.x] = 0.f;   // zero stats accumulators (pre-kC1)
        int gid = (bb * 128 + blockIdx.x) * 256 + threadIdx.x;  // init cnt (pre-kS)
        if (gid < BB * NN) ((int*)(ws + CN_OFF))[gid] = 0;
    }
    __syncthreads();

    // per-thread column n = tn (conflict-free: bank = (c+tn)%32)
    float xc[64];
#pragma unroll
    for (int c = 0; c < 64; ++c) xc[c] = xs[c * 65 + tn];

    if (og == 0 && tq == 0) {   // sq + swizzled fp16 split (one wave, per-n)
        float sqv = 0.f;
#pragma unroll
        for (int c = 0; c < 64; ++c) sqv = fmaf(xc[c], xc[c], sqv);
        int n = nbase + tn;
        ws[SQ_OFF + (size_t)bb * NN + n] = sqv;
        _Float16* xh = (_Float16*)(ws + XH_OFF);
        _Float16* xl = (_Float16*)(ws + XL_OFF);
        int tile = n >> 5, r = n & 31;
#pragma unroll
        for (int t = 0; t < 4; ++t) {
#pragma unroll
            for (int kh = 0; kh < 2; ++kh) {
                f16x8 vh, vl;
#pragma unroll
                for (int j = 0; j < 8; ++j) {
                    float v = xc[t * 16 + kh * 8 + j];
                    _Float16 h = (_Float16)v;
                    vh[j] = h;
                    vl[j] = (_Float16)((v - (float)h) * 2048.f);  // x = hi + lo*2^-11
                }
                size_t o = frag_off(bb, tile, t, kh * 32 + r);    // lane-consecutive
                *(f16x8*)&xh[o] = vh;
                *(f16x8*)&xl[o] = vl;
            }
        }
    }

    // projections: thread = n, 8 o's each (o_local = tq*8 + o2)
    float a1v[8], a2v[8];
#pragma unroll
    for (int o2 = 0; o2 < 8; ++o2) {
        int ol = tq * 8 + o2;
        const float4* w1v = (const float4*)&w1s[ol * 64];
        const float4* w2v = (const float4*)&w2s[ol * 64];
        float a1 = 0.f, a2 = 0.f;
#pragma unroll
        for (int c4 = 0; c4 < 16; ++c4) {
            float4 v1 = w1v[c4];   // broadcast ds_read_b128
            float4 v2 = w2v[c4];
            a1 = fmaf(v1.x, xc[4*c4],   a1);
            a1 = fmaf(v1.y, xc[4*c4+1], a1);
            a1 = fmaf(v1.z, xc[4*c4+2], a1);
            a1 = fmaf(v1.w, xc[4*c4+3], a1);
            a2 = fmaf(v2.x, xc[4*c4],   a2);
            a2 = fmaf(v2.y, xc[4*c4+1], a2);
            a2 = fmaf(v2.z, xc[4*c4+2], a2);
            a2 = fmaf(v2.w, xc[4*c4+3], a2);
        }
        a1v[o2] = a1;
        a2v[o2] = a2;
    }

    // y1: transpose through tb, then full-line stores (2 rows x 128 B per instr)
    const int lo = threadIdx.x & 31;          // o_local
    const int lp = (threadIdx.x >> 5) & 1;    // row parity
#pragma unroll
    for (int o2 = 0; o2 < 8; ++o2)
        tb[tn * 33 + tq * 8 + o2] = a1v[o2];
    __syncthreads();
#pragma unroll
    for (int j = 0; j < 8; ++j) {
        int r = tq * 16 + 2 * j + lp;
        ws[Y1_OFF + ((size_t)bb * NN + nbase + r) * 64 + obase + lo] = tb[r * 33 + lo];
    }
    __syncthreads();
#pragma unroll
    for (int o2 = 0; o2 < 8; ++o2)
        tb[tn * 33 + tq * 8 + o2] = a2v[o2];
    __syncthreads();
#pragma unroll
    for (int j = 0; j < 8; ++j) {
        int r = tq * 16 + 2 * j + lp;
        ws[Y2_OFF + ((size_t)bb * NN + nbase + r) * 64 + obase + lo] = tb[r * 33 + lo];
    }
}

// ---------------- kernel T (phase-0): half-sample top-20 lists, branchless networks ----------------
__global__ void __launch_bounds__(256, 3)
kT(const _Float16* __restrict__ xh, const _Float16* __restrict__ xl,
   const float* __restrict__ sq, float* __restrict__ thrL) {
    __shared__ float mrg[32 * 128];          // [j][wave*32+qc]
    __shared__ __align__(16) float sqs[1024];  // staged sq slice (lgkmcnt path)
    const int tid  = threadIdx.x;
    const int lane = tid & 63;
    const int wv   = tid >> 6;
    const int qcol = lane & 31;
    const int kh   = lane >> 5;
    const int b     = blockIdx.y >> 1;
    const int s     = blockIdx.y & 1;     // sample half
    const int qbase = blockIdx.x * 32;

    for (int i = tid; i < 1024; i += 256)
        sqs[i] = sq[(size_t)b * NN + s * 1024 + i];

    f16x8 Qh[4], Ql[4];
    load_qfrag(xh, xl, b, qbase, lane, Qh, Ql);
    __syncthreads();

    float dk[32];
#pragma unroll
    for (int i = 0; i < 32; ++i) dk[i] = FLT_MAX;

    const int p0 = s * 1024 + wv * 256;
    for (int pt = p0; pt < p0 + 256; pt += 32) {
        f16x8 Ah[4], Al[4];
        load_atile(xh, xl, b, pt >> 5, lane, Ah, Al);
        float dv[16];
        dist_from_frags(Ah, Al, sqs, pt - s * 1024, kh, Qh, Ql, dv);
        float m16 = dv[0];
#pragma unroll
        for (int i = 1; i < 16; ++i) m16 = fminf(m16, dv[i]);
        if (__any(m16 < dk[KK - 1])) {   // wave-uniform tile skip (late tiles)
            sort16(dv);
            merge32_16(dk, dv);
        }
    }

    // kh pair merge via shfl (branchless; kh==1 lanes self-merge harmlessly)
    {
        float B[32];
#pragma unroll
        for (int j = 0; j < 32; ++j) B[j] = __shfl(dk[j], lane | 32);
        merge32_32(dk, B);
    }
    if (kh == 0) {
#pragma unroll
        for (int j = 0; j < 32; ++j) mrg[j * 128 + wv * 32 + qcol] = dk[j];
    }
    __syncthreads();

    // cross-wave merge: wave 0, lanes 0-31, one query per lane; emit sorted 20-list
    if (tid < 32) {
        float B[32];
#pragma unroll 1
        for (int w = 1; w < 4; ++w) {
#pragma unroll
            for (int j = 0; j < 32; ++j) B[j] = mrg[j * 128 + w * 32 + tid];
            merge32_32(dk, B);
        }
        size_t base = (((size_t)b * 2 + s) * NN + qbase + tid) * KK;
#pragma unroll
        for (int j = 0; j < KK; ++j) thrL[base + j] = dk[j];
    }
}

// ---------------- kernel M2: exact union 20th via k-th-of-two-sorted identity ----------------
// r18: ans = min_{i=0..20} max(A[i-1], B[19-i]) -- 10 independent float4 loads +
// 41 min/max, replacing 40 serial data-dependent loads (pointer-chase).
__global__ void kM2(const float* __restrict__ thrL, float* __restrict__ thr) {
    int gid = blockIdx.x * 256 + threadIdx.x;      // 0 .. B*N-1
    int b = gid >> 13, q = gid & (NN - 1);
    float A[KK], Bv[KK];
    const float4* pa = (const float4*)&thrL[(((size_t)b * 2 + 0) * NN + q) * KK];
    const float4* pb = (const float4*)&thrL[(((size_t)b * 2 + 1) * NN + q) * KK];
#pragma unroll
    for (int i = 0; i < 5; ++i) {
        float4 va = pa[i];
        float4 vb = pb[i];
        A[4*i] = va.x;  A[4*i+1] = va.y;  A[4*i+2] = va.z;  A[4*i+3] = va.w;
        Bv[4*i] = vb.x; Bv[4*i+1] = vb.y; Bv[4*i+2] = vb.z; Bv[4*i+3] = vb.w;
    }
    float v = fminf(Bv[KK - 1], A[KK - 1]);        // i=0 and i=20 boundary terms
#pragma unroll
    for (int i = 1; i < KK; ++i)
        v = fminf(v, fmaxf(A[i - 1], Bv[KK - 1 - i]));
    // kT/kS share bitwise-identical d; tiny inflation is pure safety margin
    thr[gid] = v + fabsf(v) * 1e-6f + 1e-6f;
}

// ---------------- kernel S (phase-1): global_load_lds-staged sweep (plateau: ~95 us) ----------------
__global__ void __launch_bounds__(256, 4)
kS(const _Float16* __restrict__ xh, const _Float16* __restrict__ xl,
   const float* __restrict__ sq, const float* __restrict__ thr,
   int* __restrict__ cnt, u64* __restrict__ cand) {
    __shared__ __align__(16) char tbuf[2][8192];   // hi 4 KB + lo 4 KB per tile
    __shared__ u64 lbuf[256 * RBS];                // 20 KB
    __shared__ __align__(16) float sqs[CHUNK];     // 4 KB
    const int tid  = threadIdx.x;
    const int lane = tid & 63;
    const int wv   = tid >> 6;
    const int qcol = lane & 31;
    const int kh   = lane >> 5;
    const int id     = blockIdx.x;        // 1024 = 8 chunk x 64 qtile x 2 b
    const int ychunk = id & 7;            // XCD-pinned chunk (neutral-or-better)
    const int qt     = (id >> 3) & 63;
    const int b      = (id >> 9) & 1;
    const int qbase  = qt * QB + wv * 32;
    const int pbase0 = ychunk * CHUNK;
    const int ptile0 = pbase0 >> 5;

    // async DMA one 8 KB tile into buf: wave wv moves segment wv of hi and lo.
    auto stage = [&](int ptile, char* buf) {
        const _Float16* gh = &xh[frag_off(b, ptile, wv, lane)];
        const _Float16* gl = &xl[frag_off(b, ptile, wv, lane)];
        __builtin_amdgcn_global_load_lds(
            (const __attribute__((address_space(1))) void*)gh,
            (__attribute__((address_space(3))) void*)(buf + wv * 1024), 16, 0, 0);
        __builtin_amdgcn_global_load_lds(
            (const __attribute__((address_space(1))) void*)gl,
            (__attribute__((address_space(3))) void*)(buf + 4096 + wv * 1024), 16, 0, 0);
    };

    for (int i = tid; i < CHUNK; i += 256)
        sqs[i] = sq[(size_t)b * NN + pbase0 + i];

    f16x8 Qh[4], Ql[4];
    load_qfrag(xh, xl, b, qbase, lane, Qh, Ql);

    const size_t qidx = (size_t)b * NN + qbase + qcol;
    const float tv = thr[qidx];
    const size_t cb = qidx * CAPQ;
    int c_ = 0;

    stage(ptile0, tbuf[0]);
    __syncthreads();   // drains stage DMA (vmcnt) + sqs stores (lgkm)

    // one atomic per flush (normally once per lane, at the end)
    auto flushS = [&]() {
        if (c_ > 0) {
            int base = atomicAdd(&cnt[qidx], c_);
#pragma unroll 1
            for (int j = 0; j < c_; ++j) {
                int slot = base + j;
                if (slot < CAPQ) cand[cb + slot] = lbuf[tid * RBS + j];
            }
            c_ = 0;
        }
    };

#pragma unroll 1
    for (int tt = 0; tt < CHUNK / 32; ++tt) {
        if (tt + 1 < CHUNK / 32)
            stage(ptile0 + tt + 1, tbuf[(tt + 1) & 1]);   // async, in flight

        const char* cbuf = tbuf[tt & 1];
        f16x8 Ah[4], Al[4];
#pragma unroll
        for (int t = 0; t < 4; ++t) {
            Ah[t] = *(const f16x8*)(cbuf + t * 1024 + lane * 16);          // ds_read_b128
            Al[t] = *(const f16x8*)(cbuf + 4096 + t * 1024 + lane * 16);
        }
        float dv[16];
        dist_from_frags(Ah, Al, sqs, tt * 32, kh, Qh, Ql, dv);

        const int pb4 = pbase0 + tt * 32 + 4 * kh;
#pragma unroll
        for (int i = 0; i < 16; ++i) {
            float d = dv[i];
            if (d <= tv) {                           // rare (~1% of pairs)
                int id2 = pb4 + ((i & 3) + 8 * (i >> 2));
                lbuf[tid * RBS + c_] = ((u64)fmap(d) << 32) | (unsigned)id2;
                if (++c_ == RB) flushS();            // exact, rare overflow guard
            }
        }
        __syncthreads();   // stage(tt+1) complete; all waves done with cbuf
    }
    flushS();
}

// ---------------- kernel P (phase-2): exact top-K, 4 lanes per query ----------------
// r18: batched independent loads (no per-iteration wave break), 4-way slot split
// (1024 waves = 4/CU), two shfl merge levels. u64 keys = exact total order.
__global__ void __launch_bounds__(256)
kP(const int* __restrict__ cnt, const u64* __restrict__ cand,
   int* __restrict__ idxK) {
    const int tid  = threadIdx.x;
    const int par  = tid & 3;            // slot parity (0..3)
    const int q = blockIdx.x * 64 + (tid >> 2);
    int m = cnt[q];
    m = m < CAPQ ? m : CAPQ;
    const int nj = (m - par + 3) >> 2;   // my slots: par, par+4, ...

    // wave-max of nj (loop bound), once
    int njW = nj;
#pragma unroll
    for (int s2 = 32; s2 >= 1; s2 >>= 1) {
        int o = __shfl_xor(njW, s2);
        njW = njW > o ? njW : o;
    }

    u64 kk[KK];
#pragma unroll
    for (int i = 0; i < KK; ++i) kk[i] = ~0ull;

    auto insU = [&](u64 v) {
        kk[KK - 1] = v;
#pragma unroll
        for (int i = KK - 1; i > 0; --i) {
            u64 a = kk[i - 1], c = kk[i];
            bool sw = c < a;
            kk[i - 1] = sw ? c : a;
            kk[i]     = sw ? a : c;
        }
    };

    const u64* cp = &cand[(size_t)q * CAPQ + par];
#pragma unroll 1
    for (int j = 0; j < njW; j += 2) {       // j even; 4*(j+1)+par <= 191 in-bounds
        u64 v0 = cp[4 * j];                  // independent loads, batch-issued
        u64 v1 = cp[4 * (j + 1)];
        bool i0 = (j < nj) && v0 < kk[KK - 1];
        bool i1 = (j + 1 < nj) && v1 < kk[KK - 1];
        if (__any(i0 || i1)) {
            if (i0) insU(v0);
            if (i1 && v1 < kk[KK - 1]) insU(v1);
        }
    }

    // merge levels: par^2 then par^1 (lists sorted ascending -> early break ok)
#pragma unroll
    for (int s2 = 2; s2 >= 1; s2 >>= 1) {
        bool absorb = (par & s2) == 0;
#pragma unroll 1
        for (int j = 0; j < KK; ++j) {
            u64 v = __shfl_xor(kk[j], s2);
            bool ins = absorb && v < kk[KK - 1];
            if (!__any(ins)) break;
            if (ins) insU(v);
        }
    }

    if (par == 0) {
        int* op = &idxK[(size_t)q * KK];
#pragma unroll
        for (int i = 0; i < KK; ++i) op[i] = (int)(unsigned)(kk[i] & 0xffffffffu);
    }
}

// ---------------- kernel C1: gather + stats + hmax/hmin (o-major out) ----------------
// r18: gather loads batched into registers (independent issue) before accumulate.
__global__ void __launch_bounds__(256, 2)
kC1(const float* __restrict__ y1, const float* __restrict__ y2,
    const int* __restrict__ idxK, float* __restrict__ hmaxT,
    float* __restrict__ hminT, float* __restrict__ stats) {
    __shared__ int li[32 * KK];          // all 640 neighbor indices, staged once
    __shared__ float red[256];
    __shared__ float thm[32 * 65];       // [n_local][o], pad 65 -> conflict-free
    __shared__ float thn[32 * 65];
    int b = blockIdx.y;
    int o = threadIdx.x & 63;
    int nn = threadIdx.x >> 6;
    int nbase = blockIdx.x * 32;

    for (int i = threadIdx.x; i < 32 * KK; i += 256)
        li[i] = idxK[((size_t)b * NN + nbase) * KK + i];
    __syncthreads();

    float s = 0.f, ss = 0.f;
    for (int gidx = 0; gidx < 8; ++gidx) {
        int nl = gidx * 4 + nn;
        int n = nbase + nl;
        float y2v = y2[((size_t)b * NN + n) * 64 + o];
        const int* lin = &li[nl * KK];
        float hv[KK];
#pragma unroll
        for (int k = 0; k < KK; ++k) {
            int j = lin[k];            // wave-uniform (nn fixed per wave)
            hv[k] = y1[((size_t)b * NN + j) * 64 + o];   // 20 independent loads
        }
        float hm = -FLT_MAX, hn = FLT_MAX;
#pragma unroll
        for (int k = 0; k < KK; ++k) {
            float h = hv[k] + y2v;
            s += h;
            ss += h * h;
            hm = fmaxf(hm, h);
            hn = fminf(hn, h);
        }
        thm[nl * 65 + o] = hm;
        thn[nl * 65 + o] = hn;
    }
    __syncthreads();

    // transposed store: 8 half-wave groups, each writes 8 o-rows
    int l = threadIdx.x & 31, g = threadIdx.x >> 5;
#pragma unroll
    for (int i = 0; i < 8; ++i) {
        int o2 = g * 8 + i;
        hmaxT[((size_t)b * 64 + o2) * NN + nbase + l] = thm[l * 65 + o2];
        hminT[((size_t)b * 64 + o2) * NN + nbase + l] = thn[l * 65 + o2];
    }

    __syncthreads();
    red[threadIdx.x] = s;
    __syncthreads();
    if (threadIdx.x < 64) {
        float v = red[o] + red[64 + o] + red[128 + o] + red[192 + o];
        atomicAdd(&stats[o], v);
    }
    __syncthreads();
    red[threadIdx.x] = ss;
    __syncthreads();
    if (threadIdx.x < 64) {
        float v = red[o] + red[64 + o] + red[128 + o] + red[192 + o];
        atomicAdd(&stats[64 + o], v);
    }
}

// ---------------- kernel C3: finalize BN + leaky + max-over-k (all coalesced) ----------------
__global__ void kC3(const float* __restrict__ hmaxT, const float* __restrict__ hminT,
                    const float* __restrict__ stats, const float* __restrict__ gamma,
                    const float* __restrict__ beta, float* __restrict__ out) {
    int o = blockIdx.x;
    int half = blockIdx.y;
    int b = blockIdx.z;
    const float c = (float)BB * NN * KK;
    float mean = stats[o] / c;
    float var = stats[64 + o] / c - mean * mean;
    float rs = rsqrtf(var + 1e-5f);
    float a = gamma[o] * rs;
    float b2 = beta[o] - a * mean;
    size_t rowb = ((size_t)b * 64 + o) * NN;
    int n0 = half * (NN / 2), n1 = n0 + NN / 2;
    for (int n = n0 + threadIdx.x; n < n1; n += 256) {
        float hm = hmaxT[rowb + n];    // coalesced
        float hn = hminT[rowb + n];
        float hs = (a >= 0.f) ? hm : hn;   // affine monotone: max or min per sign of a
        float v = a * hs + b2;
        v = (v >= 0.f) ? v : 0.2f * v;
        out[rowb + n] = v;             // coalesced
    }
}

extern "C" void kernel_launch(void* const* d_in, const int* in_sizes, int n_in,
                              void* d_out, int out_size, void* d_ws, size_t ws_size,
                              hipStream_t stream) {
    const float* x     = (const float*)d_in[0];
    const float* W     = (const float*)d_in[1];
    const float* gamma = (const float*)d_in[2];
    const float* beta  = (const float*)d_in[3];
    float* out = (float*)d_out;
    float* ws  = (float*)d_ws;

    _Float16* xh = (_Float16*)(ws + XH_OFF);
    _Float16* xl = (_Float16*)(ws + XL_OFF);
    float* sq    = ws + SQ_OFF;
    float* y1    = ws + Y1_OFF;
    float* y2    = ws + Y2_OFF;
    float* thr   = ws + TH_OFF;
    int*   cnt   = (int*)(ws + CN_OFF);
    float* thrL  = ws + TL_OFF;
    u64*   cand  = (u64*)(ws + CA_OFF);
    int*   idxK  = (int*)(ws + IX_OFF);
    float* hmaxT = ws + HX_OFF;
    float* hminT = ws + HN_OFF;
    float* stats = ws + ST_OFF;

    kA<<<dim3(NN / 64, 2, BB), 256, 0, stream>>>(x, W, ws);
    kT<<<dim3(NN / 32, 2 * BB), 256, 0, stream>>>(xh, xl, sq, thrL);
    kM2<<<dim3(BB * NN / 256), 256, 0, stream>>>(thrL, thr);
    kS<<<dim3(MS * (NN / QB) * BB), 256, 0, stream>>>(xh, xl, sq, thr, cnt, cand);
    kP<<<dim3(BB * NN / 64), 256, 0, stream>>>(cnt, cand, idxK);
    kC1<<<dim3(NN / 32, BB), 256, 0, stream>>>(y1, y2, idxK, hmaxT, hminT, stats);
    kC3<<<dim3(OO, 2, BB), 256, 0, stream>>>(hmaxT, hminT, stats, gamma, beta, out);
}

// Round 19
// 275.529 us; speedup vs baseline: 1.0624x; 1.0624x over previous
//
#include <hip/hip_runtime.h>
#include <cfloat>

#define BB 2
#define NN 8192
#define OO 64
#define KK 20
#define QB 128        // queries per kS block (4 waves x 32)
#define MS 8          // point splits in kS (L2 locality > occupancy, r12/r13)
#define CHUNK 1024    // points per kS split
#define CAPQ 192      // candidate slots per query (tight thr: mean ~80)
#define RB 9          // kS per-lane buffer depth (mean ~5/chunk)
#define RBS 10        // lbuf stride in u64; writes sparse -> conflicts moot

using f16x8  = __attribute__((ext_vector_type(8))) _Float16;
using f32x16 = __attribute__((ext_vector_type(16))) float;
typedef unsigned long long u64;

// ws layout (float units)
#define XH_OFF ((size_t)0)
#define XL_OFF (XH_OFF + (size_t)BB*NN*32)
#define SQ_OFF (XL_OFF + (size_t)BB*NN*32)        // B*N
#define Y1_OFF (SQ_OFF + (size_t)BB*NN)           // B*N*64 (n-major rows)
#define Y2_OFF (Y1_OFF + (size_t)BB*NN*64)        // B*N*64 (n-major rows)
#define TH_OFF (Y2_OFF + (size_t)BB*NN*64)        // B*N thresholds (float)
#define CN_OFF (TH_OFF + (size_t)BB*NN)           // B*N counters (int)
#define TL_OFF (CN_OFF + (size_t)BB*NN)           // 2*B*N*KK half-sample top-20 lists
#define CA_OFF (TL_OFF + (size_t)2*BB*NN*KK)      // B*N*CAPQ u64
#define IX_OFF (CA_OFF + (size_t)BB*NN*CAPQ*2)    // B*N*K (int)
#define HX_OFF (IX_OFF + (size_t)BB*NN*KK)        // B*64*N (o-major)
#define HN_OFF (HX_OFF + (size_t)BB*NN*64)        // B*64*N (o-major)
#define ST_OFF (HN_OFF + (size_t)BB*NN*64)        // 128

// MFMA-native swizzled fragment layout (verified r6-18)
__device__ __forceinline__ size_t frag_off(int b, int tile, int t, int lane) {
    return ((((size_t)b * (NN / 32) + tile) * 4 + t) * 64 + lane) * 8;
}

// order-preserving float->uint map (works for negatives too)
__device__ __forceinline__ unsigned fmap(float f) {
    unsigned u = __float_as_uint(f);
    return (u & 0x80000000u) ? ~u : (u | 0x80000000u);
}

// ---------- branchless selection primitives ----------
__device__ __forceinline__ void sort16(float* v) {      // bitonic, ascending
#pragma unroll
    for (int k = 2; k <= 16; k <<= 1) {
#pragma unroll
        for (int j = k >> 1; j > 0; j >>= 1) {
#pragma unroll
            for (int i = 0; i < 16; ++i) {
                int l = i ^ j;
                if (l > i) {
                    bool up = ((i & k) == 0);
                    float mn = fminf(v[i], v[l]);
                    float mx = fmaxf(v[i], v[l]);
                    v[i] = up ? mn : mx;
                    v[l] = up ? mx : mn;
                }
            }
        }
    }
}
__device__ __forceinline__ void bmerge32(float* A) {    // bitonic input -> ascending
#pragma unroll
    for (int j = 16; j > 0; j >>= 1) {
#pragma unroll
        for (int i = 0; i < 32; ++i) {
            if ((i & j) == 0) {
                float mn = fminf(A[i], A[i | j]);
                float mx = fmaxf(A[i], A[i | j]);
                A[i] = mn;
                A[i | j] = mx;
            }
        }
    }
}
// A(32, asc) <- 32 smallest of A U B(16, asc)
__device__ __forceinline__ void merge32_16(float* A, const float* B) {
#pragma unroll
    for (int i = 16; i < 32; ++i) A[i] = fminf(A[i], B[31 - i]);
    bmerge32(A);
}
// A(32, asc) <- 32 smallest of A U B(32, asc)
__device__ __forceinline__ void merge32_32(float* A, const float* B) {
    float t[32];
#pragma unroll
    for (int i = 0; i < 32; ++i) t[i] = fminf(A[i], B[31 - i]);
    bmerge32(t);
#pragma unroll
    for (int i = 0; i < 32; ++i) A[i] = t[i];
}

// ---------- distance tile pieces: 32 points x 32 queries, hi/lo fp16 MFMA ----------
// C: col=lane&31 (query), row = (i&3) + 8*(i>>2) + 4*kh.  Verified rounds 3-18.
__device__ __forceinline__ void load_atile(const _Float16* __restrict__ xh,
                                           const _Float16* __restrict__ xl,
                                           int b, int ptile, int lane,
                                           f16x8* Ah, f16x8* Al) {
#pragma unroll
    for (int t = 0; t < 4; ++t) {
        size_t o = frag_off(b, ptile, t, lane);
        Ah[t] = *(const f16x8*)&xh[o];   // coalesced: 64 lanes x 16 B contiguous
        Al[t] = *(const f16x8*)&xl[o];
    }
}

// sqs: LDS-staged sq slice (lgkmcnt path, keeps A loads alone on vmcnt)
__device__ __forceinline__ void dist_from_frags(const f16x8* Ah, const f16x8* Al,
                                                const float* sqs, int sbase, int kh,
                                                const f16x8* Qh, const f16x8* Ql,
                                                float* dv) {
    f32x16 c0, c1;
#pragma unroll
    for (int i = 0; i < 16; ++i) { c0[i] = 0.f; c1[i] = 0.f; }
#pragma unroll
    for (int t = 0; t < 4; ++t) {
        c0 = __builtin_amdgcn_mfma_f32_32x32x16_f16(Ah[t], Qh[t], c0, 0, 0, 0); // hi*hi
        c1 = __builtin_amdgcn_mfma_f32_32x32x16_f16(Ah[t], Ql[t], c1, 0, 0, 0); // hi*lo
        c1 = __builtin_amdgcn_mfma_f32_32x32x16_f16(Al[t], Qh[t], c1, 0, 0, 0); // lo*hi
    }
#pragma unroll
    for (int r2 = 0; r2 < 4; ++r2) {
        float4 sv = *(const float4*)&sqs[sbase + 8 * r2 + 4 * kh];  // LDS broadcast
        float svv[4] = {sv.x, sv.y, sv.z, sv.w};
#pragma unroll
        for (int j = 0; j < 4; ++j) {
            int i = r2 * 4 + j;
            float d = fmaf(-2.f, c0[i], svv[j]);      // d = sq[p] - 2*dot (sq[q] const)
            dv[i] = fmaf(-9.765625e-4f, c1[i], d);    // cross terms * 2 * 2^-11
        }
    }
}

__device__ __forceinline__ void load_qfrag(const _Float16* __restrict__ xh,
                                           const _Float16* __restrict__ xl,
                                           int b, int qbase, int lane,
                                           f16x8* Qh, f16x8* Ql) {
    const int qtile = qbase >> 5;
#pragma unroll
    for (int t = 0; t < 4; ++t) {
        size_t o = frag_off(b, qtile, t, lane);
        Qh[t] = *(const f16x8*)&xh[o];
        Ql[t] = *(const f16x8*)&xl[o];
    }
}

// ---------------- kernel A: sq + fp16 hi/lo split (swizzled) + y1/y2 ----------------
// r17 structure: x staged in LDS once; o-split into 2 groups of 32.
__global__ void __launch_bounds__(256, 2)
kA(const float* __restrict__ x, const float* __restrict__ W,
   float* __restrict__ ws) {
    __shared__ __align__(16) float w1s[32 * 64];   // 8 KB: this block's 32 o rows
    __shared__ __align__(16) float w2s[32 * 64];   // 8 KB
    __shared__ float xs[64 * 65];                  // 16.6 KB [c][n], pad 65
    __shared__ float tb[64 * 33];                  // 8.4 KB transpose, pad 33
    const int bb = blockIdx.z;
    const int og = blockIdx.y;        // o-group: 0 or 1
    const int obase = og * 32;
    const int nbase = blockIdx.x * 64;
    const int tn = threadIdx.x & 63, tq = threadIdx.x >> 6;

    // W slice (32 o x 64 c), w2 = W_right - W_left
    for (int i = threadIdx.x; i < 2048; i += 256) {
        int ol = i >> 6, c = i & 63;
        float a = W[(obase + ol) * 128 + c];
        float d = W[(obase + ol) * 128 + 64 + c];
        w1s[i] = a;
        w2s[i] = d - a;
    }
    // x tile: [c][n] staged coalesced (256 B per row-segment)
    for (int i = threadIdx.x; i < 4096; i += 256) {
        int c = i >> 6, nl = i & 63;
        xs[c * 65 + nl] = x[((size_t)bb * 64 + c) * NN + nbase + nl];
    }
    if (og == 0) {
        if (blockIdx.x == 0 && bb == 0 && threadIdx.x < 128)
            ws[ST_OFF + threadIdx.x] = 0.f;   // zero stats accumulators (pre-kC1)
        int gid = (bb * 128 + blockIdx.x) * 256 + threadIdx.x;  // init cnt (pre-kS)
        if (gid < BB * NN) ((int*)(ws + CN_OFF))[gid] = 0;
    }
    __syncthreads();

    // per-thread column n = tn (conflict-free: bank = (c+tn)%32)
    float xc[64];
#pragma unroll
    for (int c = 0; c < 64; ++c) xc[c] = xs[c * 65 + tn];

    if (og == 0 && tq == 0) {   // sq + swizzled fp16 split (one wave, per-n)
        float sqv = 0.f;
#pragma unroll
        for (int c = 0; c < 64; ++c) sqv = fmaf(xc[c], xc[c], sqv);
        int n = nbase + tn;
        ws[SQ_OFF + (size_t)bb * NN + n] = sqv;
        _Float16* xh = (_Float16*)(ws + XH_OFF);
        _Float16* xl = (_Float16*)(ws + XL_OFF);
        int tile = n >> 5, r = n & 31;
#pragma unroll
        for (int t = 0; t < 4; ++t) {
#pragma unroll
            for (int kh = 0; kh < 2; ++kh) {
                f16x8 vh, vl;
#pragma unroll
                for (int j = 0; j < 8; ++j) {
                    float v = xc[t * 16 + kh * 8 + j];
                    _Float16 h = (_Float16)v;
                    vh[j] = h;
                    vl[j] = (_Float16)((v - (float)h) * 2048.f);  // x = hi + lo*2^-11
                }
                size_t o = frag_off(bb, tile, t, kh * 32 + r);    // lane-consecutive
                *(f16x8*)&xh[o] = vh;
                *(f16x8*)&xl[o] = vl;
            }
        }
    }

    // projections: thread = n, 8 o's each (o_local = tq*8 + o2)
    float a1v[8], a2v[8];
#pragma unroll
    for (int o2 = 0; o2 < 8; ++o2) {
        int ol = tq * 8 + o2;
        const float4* w1v = (const float4*)&w1s[ol * 64];
        const float4* w2v = (const float4*)&w2s[ol * 64];
        float a1 = 0.f, a2 = 0.f;
#pragma unroll
        for (int c4 = 0; c4 < 16; ++c4) {
            float4 v1 = w1v[c4];   // broadcast ds_read_b128
            float4 v2 = w2v[c4];
            a1 = fmaf(v1.x, xc[4*c4],   a1);
            a1 = fmaf(v1.y, xc[4*c4+1], a1);
            a1 = fmaf(v1.z, xc[4*c4+2], a1);
            a1 = fmaf(v1.w, xc[4*c4+3], a1);
            a2 = fmaf(v2.x, xc[4*c4],   a2);
            a2 = fmaf(v2.y, xc[4*c4+1], a2);
            a2 = fmaf(v2.z, xc[4*c4+2], a2);
            a2 = fmaf(v2.w, xc[4*c4+3], a2);
        }
        a1v[o2] = a1;
        a2v[o2] = a2;
    }

    // y1: transpose through tb, then full-line stores (2 rows x 128 B per instr)
    const int lo = threadIdx.x & 31;          // o_local
    const int lp = (threadIdx.x >> 5) & 1;    // row parity
#pragma unroll
    for (int o2 = 0; o2 < 8; ++o2)
        tb[tn * 33 + tq * 8 + o2] = a1v[o2];
    __syncthreads();
#pragma unroll
    for (int j = 0; j < 8; ++j) {
        int r = tq * 16 + 2 * j + lp;
        ws[Y1_OFF + ((size_t)bb * NN + nbase + r) * 64 + obase + lo] = tb[r * 33 + lo];
    }
    __syncthreads();
#pragma unroll
    for (int o2 = 0; o2 < 8; ++o2)
        tb[tn * 33 + tq * 8 + o2] = a2v[o2];
    __syncthreads();
#pragma unroll
    for (int j = 0; j < 8; ++j) {
        int r = tq * 16 + 2 * j + lp;
        ws[Y2_OFF + ((size_t)bb * NN + nbase + r) * 64 + obase + lo] = tb[r * 33 + lo];
    }
}

// ---------------- kernel T (phase-0): half-sample top-20 lists, branchless networks ----------------
__global__ void __launch_bounds__(256, 3)
kT(const _Float16* __restrict__ xh, const _Float16* __restrict__ xl,
   const float* __restrict__ sq, float* __restrict__ thrL) {
    __shared__ float mrg[32 * 128];          // [j][wave*32+qc]
    __shared__ __align__(16) float sqs[1024];  // staged sq slice (lgkmcnt path)
    const int tid  = threadIdx.x;
    const int lane = tid & 63;
    const int wv   = tid >> 6;
    const int qcol = lane & 31;
    const int kh   = lane >> 5;
    const int b     = blockIdx.y >> 1;
    const int s     = blockIdx.y & 1;     // sample half
    const int qbase = blockIdx.x * 32;

    for (int i = tid; i < 1024; i += 256)
        sqs[i] = sq[(size_t)b * NN + s * 1024 + i];

    f16x8 Qh[4], Ql[4];
    load_qfrag(xh, xl, b, qbase, lane, Qh, Ql);
    __syncthreads();

    float dk[32];
#pragma unroll
    for (int i = 0; i < 32; ++i) dk[i] = FLT_MAX;

    const int p0 = s * 1024 + wv * 256;
    for (int pt = p0; pt < p0 + 256; pt += 32) {
        f16x8 Ah[4], Al[4];
        load_atile(xh, xl, b, pt >> 5, lane, Ah, Al);
        float dv[16];
        dist_from_frags(Ah, Al, sqs, pt - s * 1024, kh, Qh, Ql, dv);
        float m16 = dv[0];
#pragma unroll
        for (int i = 1; i < 16; ++i) m16 = fminf(m16, dv[i]);
        if (__any(m16 < dk[KK - 1])) {   // wave-uniform tile skip (late tiles)
            sort16(dv);
            merge32_16(dk, dv);
        }
    }

    // kh pair merge via shfl (branchless; kh==1 lanes self-merge harmlessly)
    {
        float B[32];
#pragma unroll
        for (int j = 0; j < 32; ++j) B[j] = __shfl(dk[j], lane | 32);
        merge32_32(dk, B);
    }
    if (kh == 0) {
#pragma unroll
        for (int j = 0; j < 32; ++j) mrg[j * 128 + wv * 32 + qcol] = dk[j];
    }
    __syncthreads();

    // cross-wave merge: wave 0, lanes 0-31, one query per lane; emit sorted 20-list
    if (tid < 32) {
        float B[32];
#pragma unroll 1
        for (int w = 1; w < 4; ++w) {
#pragma unroll
            for (int j = 0; j < 32; ++j) B[j] = mrg[j * 128 + w * 32 + tid];
            merge32_32(dk, B);
        }
        size_t base = (((size_t)b * 2 + s) * NN + qbase + tid) * KK;
#pragma unroll
        for (int j = 0; j < KK; ++j) thrL[base + j] = dk[j];
    }
}

// ---------------- kernel M2: exact union 20th via k-th-of-two-sorted identity ----------------
// r18-keep: ans = min_{i} max(A[i-1], B[19-i]) -- 10 independent float4 loads.
__global__ void kM2(const float* __restrict__ thrL, float* __restrict__ thr) {
    int gid = blockIdx.x * 256 + threadIdx.x;      // 0 .. B*N-1
    int b = gid >> 13, q = gid & (NN - 1);
    float A[KK], Bv[KK];
    const float4* pa = (const float4*)&thrL[(((size_t)b * 2 + 0) * NN + q) * KK];
    const float4* pb = (const float4*)&thrL[(((size_t)b * 2 + 1) * NN + q) * KK];
#pragma unroll
    for (int i = 0; i < 5; ++i) {
        float4 va = pa[i];
        float4 vb = pb[i];
        A[4*i] = va.x;  A[4*i+1] = va.y;  A[4*i+2] = va.z;  A[4*i+3] = va.w;
        Bv[4*i] = vb.x; Bv[4*i+1] = vb.y; Bv[4*i+2] = vb.z; Bv[4*i+3] = vb.w;
    }
    float v = fminf(Bv[KK - 1], A[KK - 1]);        // i=0 and i=20 boundary terms
#pragma unroll
    for (int i = 1; i < KK; ++i)
        v = fminf(v, fmaxf(A[i - 1], Bv[KK - 1 - i]));
    // kT/kS share bitwise-identical d; tiny inflation is pure safety margin
    thr[gid] = v + fabsf(v) * 1e-6f + 1e-6f;
}

// ---------------- kernel S (phase-1): global_load_lds-staged sweep (plateau: ~90 us) ----------------
__global__ void __launch_bounds__(256, 4)
kS(const _Float16* __restrict__ xh, const _Float16* __restrict__ xl,
   const float* __restrict__ sq, const float* __restrict__ thr,
   int* __restrict__ cnt, u64* __restrict__ cand) {
    __shared__ __align__(16) char tbuf[2][8192];   // hi 4 KB + lo 4 KB per tile
    __shared__ u64 lbuf[256 * RBS];                // 20 KB
    __shared__ __align__(16) float sqs[CHUNK];     // 4 KB
    const int tid  = threadIdx.x;
    const int lane = tid & 63;
    const int wv   = tid >> 6;
    const int qcol = lane & 31;
    const int kh   = lane >> 5;
    const int id     = blockIdx.x;        // 1024 = 8 chunk x 64 qtile x 2 b
    const int ychunk = id & 7;            // XCD-pinned chunk (neutral-or-better)
    const int qt     = (id >> 3) & 63;
    const int b      = (id >> 9) & 1;
    const int qbase  = qt * QB + wv * 32;
    const int pbase0 = ychunk * CHUNK;
    const int ptile0 = pbase0 >> 5;

    // async DMA one 8 KB tile into buf: wave wv moves segment wv of hi and lo.
    auto stage = [&](int ptile, char* buf) {
        const _Float16* gh = &xh[frag_off(b, ptile, wv, lane)];
        const _Float16* gl = &xl[frag_off(b, ptile, wv, lane)];
        __builtin_amdgcn_global_load_lds(
            (const __attribute__((address_space(1))) void*)gh,
            (__attribute__((address_space(3))) void*)(buf + wv * 1024), 16, 0, 0);
        __builtin_amdgcn_global_load_lds(
            (const __attribute__((address_space(1))) void*)gl,
            (__attribute__((address_space(3))) void*)(buf + 4096 + wv * 1024), 16, 0, 0);
    };

    for (int i = tid; i < CHUNK; i += 256)
        sqs[i] = sq[(size_t)b * NN + pbase0 + i];

    f16x8 Qh[4], Ql[4];
    load_qfrag(xh, xl, b, qbase, lane, Qh, Ql);

    const size_t qidx = (size_t)b * NN + qbase + qcol;
    const float tv = thr[qidx];
    const size_t cb = qidx * CAPQ;
    int c_ = 0;

    stage(ptile0, tbuf[0]);
    __syncthreads();   // drains stage DMA (vmcnt) + sqs stores (lgkm)

    // one atomic per flush (normally once per lane, at the end)
    auto flushS = [&]() {
        if (c_ > 0) {
            int base = atomicAdd(&cnt[qidx], c_);
#pragma unroll 1
            for (int j = 0; j < c_; ++j) {
                int slot = base + j;
                if (slot < CAPQ) cand[cb + slot] = lbuf[tid * RBS + j];
            }
            c_ = 0;
        }
    };

#pragma unroll 1
    for (int tt = 0; tt < CHUNK / 32; ++tt) {
        if (tt + 1 < CHUNK / 32)
            stage(ptile0 + tt + 1, tbuf[(tt + 1) & 1]);   // async, in flight

        const char* cbuf = tbuf[tt & 1];
        f16x8 Ah[4], Al[4];
#pragma unroll
        for (int t = 0; t < 4; ++t) {
            Ah[t] = *(const f16x8*)(cbuf + t * 1024 + lane * 16);          // ds_read_b128
            Al[t] = *(const f16x8*)(cbuf + 4096 + t * 1024 + lane * 16);
        }
        float dv[16];
        dist_from_frags(Ah, Al, sqs, tt * 32, kh, Qh, Ql, dv);

        const int pb4 = pbase0 + tt * 32 + 4 * kh;
#pragma unroll
        for (int i = 0; i < 16; ++i) {
            float d = dv[i];
            if (d <= tv) {                           // rare (~1% of pairs)
                int id2 = pb4 + ((i & 3) + 8 * (i >> 2));
                lbuf[tid * RBS + c_] = ((u64)fmap(d) << 32) | (unsigned)id2;
                if (++c_ == RB) flushS();            // exact, rare overflow guard
            }
        }
        __syncthreads();   // stage(tt+1) complete; all waves done with cbuf
    }
    flushS();
}

// ---------------- kernel P (phase-2): exact top-K, 2 lanes per query (r17 form) ----------------
__global__ void __launch_bounds__(64)
kP(const int* __restrict__ cnt, const u64* __restrict__ cand,
   int* __restrict__ idxK) {
    const int lane = threadIdx.x;
    const int qloc = lane & 31;
    const int par  = lane >> 5;          // even/odd slot parity
    const int q = blockIdx.x * 32 + qloc;
    int m = cnt[q];
    m = m < CAPQ ? m : CAPQ;
    const int nj = (m - par + 1) >> 1;   // my slot count: par, par+2, ...
    u64 kk[KK];
#pragma unroll
    for (int i = 0; i < KK; ++i) kk[i] = ~0ull;

    auto insU = [&](u64 v) {
        kk[KK - 1] = v;
#pragma unroll
        for (int i = KK - 1; i > 0; --i) {
            u64 a = kk[i - 1], c = kk[i];
            bool sw = c < a;
            kk[i - 1] = sw ? c : a;
            kk[i]     = sw ? a : c;
        }
    };

    const u64* cp = &cand[(size_t)q * CAPQ + par];
#pragma unroll 1
    for (int j = 0; j < CAPQ / 2; ++j) {
        if (!__any(j < nj)) break;
        u64 v = cp[2 * j];               // in-bounds; stale slots gated below
        if ((j < nj) && v < kk[KK - 1]) insU(v);
    }

    // parity pair merge via shfl (u64 keys: exact (d,idx) lexicographic order)
#pragma unroll
    for (int j = 0; j < KK; ++j) {
        u64 v = __shfl(kk[j], lane | 32);
        bool ins = (par == 0) && v < kk[KK - 1];
        if (!__any(ins)) break;          // partner sorted ascending
        if (ins) insU(v);
    }

    if (par == 0) {
        int* op = &idxK[(size_t)q * KK];
#pragma unroll
        for (int i = 0; i < KK; ++i) op[i] = (int)(unsigned)(kk[i] & 0xffffffffu);
    }
}

// ---------------- kernel C1: gather + stats + hmax/hmin (o-major out, r17 form) ----------------
__global__ void kC1(const float* __restrict__ y1, const float* __restrict__ y2,
                    const int* __restrict__ idxK, float* __restrict__ hmaxT,
                    float* __restrict__ hminT, float* __restrict__ stats) {
    __shared__ int li[32 * KK];          // all 640 neighbor indices, staged once
    __shared__ float red[256];
    __shared__ float thm[32 * 65];       // [n_local][o], pad 65 -> conflict-free
    __shared__ float thn[32 * 65];
    int b = blockIdx.y;
    int o = threadIdx.x & 63;
    int nn = threadIdx.x >> 6;
    int nbase = blockIdx.x * 32;

    for (int i = threadIdx.x; i < 32 * KK; i += 256)
        li[i] = idxK[((size_t)b * NN + nbase) * KK + i];
    __syncthreads();

    float s = 0.f, ss = 0.f;
    for (int gidx = 0; gidx < 8; ++gidx) {
        int nl = gidx * 4 + nn;
        int n = nbase + nl;
        float y2v = y2[((size_t)b * NN + n) * 64 + o];
        float hm = -FLT_MAX, hn = FLT_MAX;
        const int* lin = &li[nl * KK];
#pragma unroll 4
        for (int k = 0; k < KK; ++k) {
            int j = lin[k];            // wave-uniform (nn fixed per wave)
            float h = y1[((size_t)b * NN + j) * 64 + o] + y2v;   // coalesced 256B, L2-hot
            s += h;
            ss += h * h;
            hm = fmaxf(hm, h);
            hn = fminf(hn, h);
        }
        thm[nl * 65 + o] = hm;
        thn[nl * 65 + o] = hn;
    }
    __syncthreads();

    // transposed store: 8 half-wave groups, each writes 8 o-rows
    int l = threadIdx.x & 31, g = threadIdx.x >> 5;
#pragma unroll
    for (int i = 0; i < 8; ++i) {
        int o2 = g * 8 + i;
        hmaxT[((size_t)b * 64 + o2) * NN + nbase + l] = thm[l * 65 + o2];
        hminT[((size_t)b * 64 + o2) * NN + nbase + l] = thn[l * 65 + o2];
    }

    __syncthreads();
    red[threadIdx.x] = s;
    __syncthreads();
    if (threadIdx.x < 64) {
        float v = red[o] + red[64 + o] + red[128 + o] + red[192 + o];
        atomicAdd(&stats[o], v);
    }
    __syncthreads();
    red[threadIdx.x] = ss;
    __syncthreads();
    if (threadIdx.x < 64) {
        float v = red[o] + red[64 + o] + red[128 + o] + red[192 + o];
        atomicAdd(&stats[64 + o], v);
    }
}

// ---------------- kernel C3: finalize BN + leaky + max-over-k (all coalesced) ----------------
__global__ void kC3(const float* __restrict__ hmaxT, const float* __restrict__ hminT,
                    const float* __restrict__ stats, const float* __restrict__ gamma,
                    const float* __restrict__ beta, float* __restrict__ out) {
    int o = blockIdx.x;
    int half = blockIdx.y;
    int b = blockIdx.z;
    const float c = (float)BB * NN * KK;
    float mean = stats[o] / c;
    float var = stats[64 + o] / c - mean * mean;
    float rs = rsqrtf(var + 1e-5f);
    float a = gamma[o] * rs;
    float b2 = beta[o] - a * mean;
    size_t rowb = ((size_t)b * 64 + o) * NN;
    int n0 = half * (NN / 2), n1 = n0 + NN / 2;
    for (int n = n0 + threadIdx.x; n < n1; n += 256) {
        float hm = hmaxT[rowb + n];    // coalesced
        float hn = hminT[rowb + n];
        float hs = (a >= 0.f) ? hm : hn;   // affine monotone: max or min per sign of a
        float v = a * hs + b2;
        v = (v >= 0.f) ? v : 0.2f * v;
        out[rowb + n] = v;             // coalesced
    }
}

extern "C" void kernel_launch(void* const* d_in, const int* in_sizes, int n_in,
                              void* d_out, int out_size, void* d_ws, size_t ws_size,
                              hipStream_t stream) {
    const float* x     = (const float*)d_in[0];
    const float* W     = (const float*)d_in[1];
    const float* gamma = (const float*)d_in[2];
    const float* beta  = (const float*)d_in[3];
    float* out = (float*)d_out;
    float* ws  = (float*)d_ws;

    _Float16* xh = (_Float16*)(ws + XH_OFF);
    _Float16* xl = (_Float16*)(ws + XL_OFF);
    float* sq    = ws + SQ_OFF;
    float* y1    = ws + Y1_OFF;
    float* y2    = ws + Y2_OFF;
    float* thr   = ws + TH_OFF;
    int*   cnt   = (int*)(ws + CN_OFF);
    float* thrL  = ws + TL_OFF;
    u64*   cand  = (u64*)(ws + CA_OFF);
    int*   idxK  = (int*)(ws + IX_OFF);
    float* hmaxT = ws + HX_OFF;
    float* hminT = ws + HN_OFF;
    float* stats = ws + ST_OFF;

    kA<<<dim3(NN / 64, 2, BB), 256, 0, stream>>>(x, W, ws);
    kT<<<dim3(NN / 32, 2 * BB), 256, 0, stream>>>(xh, xl, sq, thrL);
    kM2<<<dim3(BB * NN / 256), 256, 0, stream>>>(thrL, thr);
    kS<<<dim3(MS * (NN / QB) * BB), 256, 0, stream>>>(xh, xl, sq, thr, cnt, cand);
    kP<<<dim3(BB * NN / 32), 64, 0, stream>>>(cnt, cand, idxK);
    kC1<<<dim3(NN / 32, BB), 256, 0, stream>>>(y1, y2, idxK, hmaxT, hminT, stats);
    kC3<<<dim3(OO, 2, BB), 256, 0, stream>>>(hmaxT, hminT, stats, gamma, beta, out);
}